// Round 5
// baseline (2231.452 us; speedup 1.0000x reference)
//
#include <hip/hip_runtime.h>
#include <cstdint>
#include <cstddef>

#define NPTS 8192
#define MCTR 2048
#define BATCH 4
#define KNB 32

// ---- u64 wave max via DPP (identity 0), broadcast from lane 63 ----
__device__ __forceinline__ unsigned long long wave_max_key(unsigned long long k) {
#define STEPK(ctrl, rmask, bmask)                                                         \
  {                                                                                       \
    int lo_ = __builtin_amdgcn_update_dpp(0, (int)(unsigned)(k & 0xffffffffull), ctrl,    \
                                          rmask, bmask, false);                           \
    int hi_ = __builtin_amdgcn_update_dpp(0, (int)(unsigned)(k >> 32), ctrl, rmask,       \
                                          bmask, false);                                  \
    unsigned long long o_ =                                                               \
        ((unsigned long long)(unsigned)hi_ << 32) | (unsigned)lo_;                        \
    k = k > o_ ? k : o_;                                                                  \
  }
  STEPK(0x111, 0xf, 0xf)  // row_shr:1
  STEPK(0x112, 0xf, 0xf)  // row_shr:2
  STEPK(0x114, 0xf, 0xf)  // row_shr:4
  STEPK(0x118, 0xf, 0xf)  // row_shr:8
  STEPK(0x142, 0xa, 0xf)  // row_bcast:15
  STEPK(0x143, 0xc, 0xf)  // row_bcast:31
#undef STEPK
  int lo = __builtin_amdgcn_readlane((int)(unsigned)(k & 0xffffffffull), 63);
  int hi = __builtin_amdgcn_readlane((int)(unsigned)(k >> 32), 63);
  return ((unsigned long long)(unsigned)hi << 32) | (unsigned)lo;
}

__device__ __forceinline__ unsigned long long u64max(unsigned long long a,
                                                     unsigned long long b) {
  return a > b ? a : b;
}

// ---------- feature transpose (B,32,N) -> (B,N,32) ----------
__global__ __launch_bounds__(256) void featT_kernel(const float* __restrict__ feats,
                                                    float* __restrict__ featT) {
  const int bn = blockIdx.x;
  const int b = bn >> 8;
  const int n0 = (bn & 255) * 32;
  __shared__ float tile[32][33];
  const int tx = threadIdx.x & 31, ty = threadIdx.x >> 5;
  const float* src = feats + (size_t)b * 32 * NPTS;
#pragma unroll
  for (int s = 0; s < 4; ++s) {
    int f = ty + 8 * s;
    tile[f][tx] = src[(size_t)f * NPTS + n0 + tx];
  }
  __syncthreads();
  float* dst = featT + ((size_t)b * NPTS + n0) * 32;
#pragma unroll
  for (int s = 0; s < 4; ++s) {
    int n = ty + 8 * s;
    dst[n * 32 + tx] = tile[tx][n];
  }
}

// ---------- weight transpose ----------
__global__ __launch_bounds__(256) void prep_kernel(const float* __restrict__ W1,
                                                   const float* __restrict__ W2,
                                                   const float* __restrict__ W3,
                                                   float* __restrict__ Wt) {
  const int t = blockIdx.x * 256 + threadIdx.x;
  if (t < 2240) { int c = t >> 6, o = t & 63;  Wt[t] = W1[o * 35 + c]; }
  if (t < 4096) { int c = t >> 6, o = t & 63;  Wt[2240 + t] = W2[o * 64 + c]; }
  if (t < 8192) { int c = t >> 7, o = t & 127; Wt[6336 + t] = W3[o * 64 + c]; }
}

// ---------- counting sort by x-bucket (512 buckets), one block per batch ----------
// Within-bucket order is nondeterministic (atomic cursors) — harmless: all
// downstream selection is keyed on (distance, ORIGINAL index), never on slot order.
__global__ __launch_bounds__(512) void xsort_kernel(const float* __restrict__ coords,
                                                    float* __restrict__ sX,
                                                    float* __restrict__ sY,
                                                    float* __restrict__ sZ,
                                                    int* __restrict__ sOrig) {
  const int b = blockIdx.x;
  const int tid = threadIdx.x;
  const float* C = coords + (size_t)b * 3 * NPTS;
  __shared__ int h[512];
  __shared__ int cur[512];
  h[tid] = 0;
  __syncthreads();
  int bk[16];
#pragma unroll
  for (int j = 0; j < 16; ++j) {
    int i = tid + j * 512;
    float x = C[i];
    int k = (int)(x * 512.0f);
    k = k < 0 ? 0 : (k > 511 ? 511 : k);
    bk[j] = k;
    atomicAdd(&h[k], 1);
  }
  __syncthreads();
  const int cnt = h[tid];
  for (int s = 1; s < 512; s <<= 1) {  // Hillis-Steele inclusive scan
    int v = (tid >= s) ? h[tid - s] : 0;
    __syncthreads();
    h[tid] += v;
    __syncthreads();
  }
  cur[tid] = h[tid] - cnt;  // exclusive start of bucket tid
  __syncthreads();
  float* dX = sX + (size_t)b * NPTS;
  float* dY = sY + (size_t)b * NPTS;
  float* dZ = sZ + (size_t)b * NPTS;
  int* dO = sOrig + (size_t)b * NPTS;
#pragma unroll
  for (int j = 0; j < 16; ++j) {
    int i = tid + j * 512;
    int pos = atomicAdd(&cur[bk[j]], 1);
    dX[pos] = C[i];
    dY[pos] = C[NPTS + i];
    dZ[pos] = C[2 * NPTS + i];
    dO[pos] = i;
  }
}

// ---------- furthest point sampling with exact bbox culling ----------
// 512 threads; thread t owns 16 x-sorted slots [16t,16t+16) (registers).
// Skip rule (exact): if lb*(1-1e-6) >= cmax, no dd in the block can change under
// the reference's fp32 rounding (margin >> 8 ulp of the d2 chains).
// Winner key = (distbits<<32)|((8191-orig)<<13)|slot -> (max dist, min ORIG idx).
__global__ __launch_bounds__(512) void fps_kernel(const float* __restrict__ sX,
                                                  const float* __restrict__ sY,
                                                  const float* __restrict__ sZ,
                                                  const int* __restrict__ sOrig,
                                                  int* __restrict__ cidx,
                                                  float* __restrict__ centers) {
  const int b = blockIdx.x;
  const int tid = threadIdx.x;
  const int wave = tid >> 6, lane = tid & 63;
  __shared__ float lC[NPTS * 3];
  __shared__ __align__(16) unsigned long long skey[2][8];
  __shared__ int s_slot0;
  const float* gX = sX + (size_t)b * NPTS;
  const float* gY = sY + (size_t)b * NPTS;
  const float* gZ = sZ + (size_t)b * NPTS;
  const int* gO = sOrig + (size_t)b * NPTS;
  for (int i = tid; i < NPTS; i += 512) {
    float x = gX[i], y = gY[i], z = gZ[i];
    lC[3 * i] = x;
    lC[3 * i + 1] = y;
    lC[3 * i + 2] = z;
  }
  const int base = tid * 16;
  int og[16];
#pragma unroll
  for (int j = 0; j < 16; ++j) {
    og[j] = gO[base + j];
    if (og[j] == 0) s_slot0 = base + j;  // exactly one thread writes
  }
  __syncthreads();
  float px[16], py[16], pz[16], dd[16];
#pragma unroll
  for (int j = 0; j < 16; ++j) {
    px[j] = lC[3 * (base + j)];
    py[j] = lC[3 * (base + j) + 1];
    pz[j] = lC[3 * (base + j) + 2];
    dd[j] = __builtin_inff();
  }
  // exact bbox of owned points
  float xlo = px[0], xhi = px[0], ylo = py[0], yhi = py[0], zlo = pz[0], zhi = pz[0];
#pragma unroll
  for (int j = 1; j < 16; ++j) {
    xlo = fminf(xlo, px[j]); xhi = fmaxf(xhi, px[j]);
    ylo = fminf(ylo, py[j]); yhi = fmaxf(yhi, py[j]);
    zlo = fminf(zlo, pz[j]); zhi = fmaxf(zhi, pz[j]);
  }
  float cmax = __builtin_inff();
  int amin17 = (og[0] << 4) | 0;
#pragma unroll
  for (int j = 1; j < 16; ++j) amin17 = min(amin17, (og[j] << 4) | j);
  int far_orig = 0;
  int slot = s_slot0;
  float cx = lC[3 * slot], cy = lC[3 * slot + 1], cz = lC[3 * slot + 2];
  unsigned long long wkey = 0;
  int buf = 0;
  for (int it = 0; it < MCTR; ++it) {
    if (tid == 0) {
      cidx[b * MCTR + it] = far_orig;
      centers[(size_t)b * 3 * MCTR + it] = cx;
      centers[(size_t)b * 3 * MCTR + MCTR + it] = cy;
      centers[(size_t)b * 3 * MCTR + 2 * MCTR + it] = cz;
    }
    // lower bound on dist^2(centroid, any owned point)
    float dxm = fmaxf(fmaxf(xlo - cx, cx - xhi), 0.0f);
    float dym = fmaxf(fmaxf(ylo - cy, cy - yhi), 0.0f);
    float dzm = fmaxf(fmaxf(zlo - cz, cz - zhi), 0.0f);
    float lb = dxm * dxm + dym * dym + dzm * dzm;
    bool active = !(lb * 0.999999f >= cmax);  // margin makes skip provably exact
    unsigned long long mk = __ballot(active ? 1 : 0);
    if (mk != 0ull) {
      if (active) {
#pragma unroll
        for (int j = 0; j < 16; ++j) {
          // EXACT reference order: (dx*dx + dy*dy) + dz*dz, rn each step, no FMA
          float dx = __fsub_rn(px[j], cx);
          float dy = __fsub_rn(py[j], cy);
          float dz = __fsub_rn(pz[j], cz);
          float d = __fadd_rn(__fadd_rn(__fmul_rn(dx, dx), __fmul_rn(dy, dy)),
                              __fmul_rn(dz, dz));
          dd[j] = fminf(dd[j], d);
        }
        float a0 = fmaxf(fmaxf(dd[0], dd[1]), dd[2]);
        float a1 = fmaxf(fmaxf(dd[3], dd[4]), dd[5]);
        float a2 = fmaxf(fmaxf(dd[6], dd[7]), dd[8]);
        float a3 = fmaxf(fmaxf(dd[9], dd[10]), dd[11]);
        float a4 = fmaxf(fmaxf(dd[12], dd[13]), dd[14]);
        cmax = fmaxf(fmaxf(fmaxf(a0, a1), a2), fmaxf(fmaxf(a3, a4), dd[15]));
        amin17 = 0x7fffffff;  // min ORIGINAL idx among achievers of cmax
#pragma unroll
        for (int j = 0; j < 16; ++j)
          amin17 = min(amin17, (dd[j] == cmax) ? ((og[j] << 4) | j) : 0x7fffffff);
      }
      unsigned long long key =
          ((unsigned long long)__float_as_uint(cmax) << 32) |
          ((unsigned long long)(unsigned)(8191 - (amin17 >> 4)) << 13) |
          (unsigned long long)(unsigned)(base + (amin17 & 15));
      wkey = wave_max_key(key);
      if (lane == 0) skey[buf][wave] = wkey;
    } else {
      if (lane == 0) skey[buf][wave] = wkey;  // nothing changed in this wave
    }
    __syncthreads();
    const ulonglong2* kp = (const ulonglong2*)skey[buf];
    ulonglong2 k0 = kp[0], k1 = kp[1], k2 = kp[2], k3 = kp[3];
    unsigned long long gk =
        u64max(u64max(u64max(k0.x, k0.y), u64max(k1.x, k1.y)),
               u64max(u64max(k2.x, k2.y), u64max(k3.x, k3.y)));
    far_orig = 8191 - (int)((gk >> 13) & 0x1fff);
    slot = (int)(gk & 0x1fff);
    cx = lC[3 * slot];
    cy = lC[3 * slot + 1];
    cz = lC[3 * slot + 2];
    buf ^= 1;
  }
}

// ---------- ball query: one wave per center, ordered first-32 collection ----------
__global__ __launch_bounds__(256) void ballq_kernel(const float* __restrict__ coords,
                                                    const int* __restrict__ cidx,
                                                    int* __restrict__ nbidx) {
  const int wib = threadIdx.x >> 6;
  const int gw = blockIdx.x * 4 + wib;
  const int lane = threadIdx.x & 63;
  const int b = gw >> 11;
  const float* C = coords + (size_t)b * 3 * NPTS;
  const int ci = cidx[gw];
  const float cx = C[ci], cy = C[NPTS + ci], cz = C[2 * NPTS + ci];
  // python double 0.2*0.2 demoted to f32 == 0x3D23D70A (NOT 0.2f*0.2f!)
  const float R2 = (float)(0.2 * 0.2);
  __shared__ int sbuf[4][32];
  int* buf = sbuf[wib];
  int count = 0;
  for (int base = 0; base < NPTS && count < 32; base += 64) {
    const int i = base + lane;
    float dx = __fsub_rn(cx, C[i]);
    float dy = __fsub_rn(cy, C[NPTS + i]);
    float dz = __fsub_rn(cz, C[2 * NPTS + i]);
    float d2 = __fadd_rn(__fadd_rn(__fmul_rn(dx, dx), __fmul_rn(dy, dy)), __fmul_rn(dz, dz));
    bool q = d2 < R2;
    unsigned long long mk = __ballot(q ? 1 : 0);
    int pos = count + (int)__popcll(mk & ((1ull << lane) - 1ull));
    if (q && pos < 32) buf[pos] = i;
    count += (int)__popcll(mk);
  }
  __syncthreads();
  if (lane < 32) {
    int cnt = count < 32 ? count : 32;
    int first = (count > 0) ? buf[0] : 0;
    int v = (lane < cnt) ? buf[lane] : first;
    nbidx[(size_t)gw * KNB + lane] = v;
  }
}

// ---------- MLP helpers ----------
__device__ __forceinline__ void layer_accum(const float* __restrict__ Wcol,
                                            const float* __restrict__ X, int Cin,
                                            int ldw, float bias, float acc[32]) {
#pragma unroll
  for (int k = 0; k < 32; ++k) acc[k] = bias;
  for (int c = 0; c < Cin; ++c) {
    float w = Wcol[c * ldw];
    const float4* xr = (const float4*)(X + c * 36);
#pragma unroll
    for (int q = 0; q < 8; ++q) {
      float4 xv = xr[q];
      acc[4 * q + 0] = fmaf(w, xv.x, acc[4 * q + 0]);
      acc[4 * q + 1] = fmaf(w, xv.y, acc[4 * q + 1]);
      acc[4 * q + 2] = fmaf(w, xv.z, acc[4 * q + 2]);
      acc[4 * q + 3] = fmaf(w, xv.w, acc[4 * q + 3]);
    }
  }
}

__device__ __forceinline__ void store_relu(float* __restrict__ row, const float acc[32]) {
#pragma unroll
  for (int q = 0; q < 8; ++q) {
    float4 v;
    v.x = fmaxf(acc[4 * q + 0], 0.f);
    v.y = fmaxf(acc[4 * q + 1], 0.f);
    v.z = fmaxf(acc[4 * q + 2], 0.f);
    v.w = fmaxf(acc[4 * q + 3], 0.f);
    *(float4*)(row + 4 * q) = v;
  }
}

// ---------- gather + 3-layer MLP + maxpool: one wave per center ----------
__global__ __launch_bounds__(64) void mlp_kernel(const float* __restrict__ coords,
                                                 const float* __restrict__ featT,
                                                 const float* __restrict__ Wt,
                                                 const float* __restrict__ b1,
                                                 const float* __restrict__ b2,
                                                 const float* __restrict__ b3,
                                                 const int* __restrict__ cidx,
                                                 const int* __restrict__ nbidx,
                                                 float* __restrict__ outT) {
  const int g = blockIdx.x;
  const int b = g >> 11;
  const int lane = threadIdx.x;
  __shared__ __align__(16) float A[64 * 36];
  __shared__ __align__(16) float Bf[64 * 36];
  const float* C = coords + (size_t)b * 3 * NPTS;
  const int ci = cidx[g];
  const float ccx = C[ci], ccy = C[NPTS + ci], ccz = C[2 * NPTS + ci];
  const int* nb = nbidx + (size_t)g * KNB;
  if (lane < 32) {
    const int n = nb[lane];
    A[0 * 36 + lane] = C[n] - ccx;
    A[1 * 36 + lane] = C[NPTS + n] - ccy;
    A[2 * 36 + lane] = C[2 * NPTS + n] - ccz;
    const float4* f = (const float4*)(featT + ((size_t)b * NPTS + n) * 32);
#pragma unroll
    for (int q = 0; q < 4; ++q) {
      float4 v = f[q];
      A[(3 + 4 * q) * 36 + lane] = v.x;
      A[(4 + 4 * q) * 36 + lane] = v.y;
      A[(5 + 4 * q) * 36 + lane] = v.z;
      A[(6 + 4 * q) * 36 + lane] = v.w;
    }
  } else {
    const int k = lane - 32;
    const int n = nb[k];
    const float4* f = (const float4*)(featT + ((size_t)b * NPTS + n) * 32);
#pragma unroll
    for (int q = 4; q < 8; ++q) {
      float4 v = f[q];
      A[(3 + 4 * q) * 36 + k] = v.x;
      A[(4 + 4 * q) * 36 + k] = v.y;
      A[(5 + 4 * q) * 36 + k] = v.z;
      A[(6 + 4 * q) * 36 + k] = v.w;
    }
  }
  __syncthreads();
  float acc[32];
  layer_accum(Wt + lane, A, 35, 64, b1[lane], acc);
  store_relu(&Bf[lane * 36], acc);
  __syncthreads();
  layer_accum(Wt + 2240 + lane, Bf, 64, 64, b2[lane], acc);
  __syncthreads();
  store_relu(&A[lane * 36], acc);
  __syncthreads();
  float* outp = outT + (size_t)g * 128;
#pragma unroll 1
  for (int h = 0; h < 2; ++h) {
    layer_accum(Wt + 6336 + h * 64 + lane, A, 64, 128, b3[h * 64 + lane], acc);
    float mx = 0.f;  // relu then max == max then clamp at 0
#pragma unroll
    for (int k = 0; k < 32; ++k) mx = fmaxf(mx, acc[k]);
    outp[h * 64 + lane] = mx;
  }
}

// ---------- output transpose (B,M,128) -> (B,128,M) ----------
__global__ __launch_bounds__(256) void outT_kernel(const float* __restrict__ outT,
                                                   float* __restrict__ out) {
  const int bid = blockIdx.x;
  const int b = bid >> 8;
  const int r = bid & 255;
  const int o0 = (r >> 6) * 32;
  const int m0 = (r & 63) * 32;
  __shared__ float tile[32][33];
  const int tx = threadIdx.x & 31, ty = threadIdx.x >> 5;
  const float* src = outT + ((size_t)b * MCTR + m0) * 128;
#pragma unroll
  for (int s = 0; s < 4; ++s) {
    int m = ty + 8 * s;
    tile[m][tx] = src[(size_t)m * 128 + o0 + tx];
  }
  __syncthreads();
  float* dst = out + ((size_t)b * 128 + o0) * MCTR + m0;
#pragma unroll
  for (int s = 0; s < 4; ++s) {
    int o = ty + 8 * s;
    dst[(size_t)o * MCTR + tx] = tile[tx][o];
  }
}

extern "C" void kernel_launch(void* const* d_in, const int* in_sizes, int n_in,
                              void* d_out, int out_size, void* d_ws, size_t ws_size,
                              hipStream_t stream) {
  (void)in_sizes; (void)n_in; (void)out_size; (void)ws_size;
  const float* feats = (const float*)d_in[0];
  const float* coords = (const float*)d_in[1];
  const float* W1 = (const float*)d_in[2];
  const float* b1 = (const float*)d_in[3];
  const float* W2 = (const float*)d_in[4];
  const float* b2 = (const float*)d_in[5];
  const float* W3 = (const float*)d_in[6];
  const float* b3 = (const float*)d_in[7];
  float* out = (float*)d_out;
  float* centers = out + (size_t)BATCH * 128 * MCTR;

  float* ws_f = (float*)d_ws;
  float* featT = ws_f;                                     // 1,048,576 f
  float* Wt = ws_f + 1048576;                              //    14,528 f
  int* cidx = (int*)(ws_f + 1048576 + 14528);              //     8,192 i
  int* nbidx = (int*)(ws_f + 1048576 + 14528 + 8192);      //   262,144 i
  float* outTbuf = ws_f + 1048576 + 14528 + 8192 + 262144; // 1,048,576 f
  // sorted-coord arrays overlay outTbuf: dead before mlp_kernel writes it
  float* sX = outTbuf;                 // 32768 f
  float* sY = outTbuf + 32768;         // 32768 f
  float* sZ = outTbuf + 65536;         // 32768 f
  int* sOrig = (int*)(outTbuf + 98304);// 32768 i   (total 512 KB < outTbuf)

  featT_kernel<<<1024, 256, 0, stream>>>(feats, featT);
  prep_kernel<<<32, 256, 0, stream>>>(W1, W2, W3, Wt);
  xsort_kernel<<<BATCH, 512, 0, stream>>>(coords, sX, sY, sZ, sOrig);
  fps_kernel<<<BATCH, 512, 0, stream>>>(sX, sY, sZ, sOrig, cidx, centers);
  ballq_kernel<<<2048, 256, 0, stream>>>(coords, cidx, nbidx);
  mlp_kernel<<<BATCH * MCTR, 64, 0, stream>>>(coords, featT, Wt, b1, b2, b3, cidx, nbidx, outTbuf);
  outT_kernel<<<1024, 256, 0, stream>>>(outTbuf, out);
}